// Round 1
// baseline (335.301 us; speedup 1.0000x reference)
//
#include <hip/hip_runtime.h>
#include <hip/hip_bf16.h>
#include <stdint.h>

// Problem constants: N=16, T=512, H=C=O=64, K=9, E=256
typedef float f32x4 __attribute__((ext_vector_type(4)));
typedef __bf16 bf16x8 __attribute__((ext_vector_type(8)));
typedef __bf16 bf16x4 __attribute__((ext_vector_type(4)));
typedef unsigned short u16;
typedef unsigned int u32;

__device__ __forceinline__ u16 f2bf(float f) {
    u32 u = __float_as_uint(f);
    u32 r = (u + 0x7fffu + ((u >> 16) & 1u)) >> 16;
    return (u16)r;
}

// ---------------------------------------------------------------- k_attn
// Fused: per-block adj build from edges (replaces k_adj), wave-autonomous
// attention (lane = h, one t per wave), plus appended weight-pack blocks
// (replaces k_pack). Grid = 2048 attn blocks + 160 pack blocks.
#define NB_ATTN 2048

__global__ __launch_bounds__(256) void k_attn(
    const float* __restrict__ X, const int* __restrict__ edges,
    const float* __restrict__ w1g, const float* __restrict__ b1g,
    const float* __restrict__ w2g, const float* __restrict__ b2g,
    const float* __restrict__ Wlin, const float* __restrict__ Wtcn,
    u16* __restrict__ wlin_p, u16* __restrict__ wtcn_p,
    float* __restrict__ diag) {
    const int tid = threadIdx.x;
    const int bid = blockIdx.x;

    if (bid >= NB_ATTN) {
        // ---- weight pack (former k_pack), MFMA B-fragment order ----
        int idx = (bid - NB_ATTN) * 256 + tid;
        if (idx < 4096) {
            int jj = idx & 7, l = (idx >> 3) & 63, j = (idx >> 9) & 3, s = idx >> 11;
            int o = j * 16 + (l & 15);
            int c = s * 32 + (l >> 4) * 8 + jj;
            wlin_p[idx] = f2bf(Wlin[o * 64 + c]);
        }
        int i2 = idx - 4096;
        if (i2 >= 0 && i2 < 36864) {
            int jj = i2 & 7, l = (i2 >> 3) & 63, j = (i2 >> 9) & 3, s = (i2 >> 11) & 1, kk = i2 >> 12;
            int o = j * 16 + (l & 15);
            int op = s * 32 + (l >> 4) * 8 + jj;
            wtcn_p[i2] = f2bf(Wtcn[(o * 64 + op) * 9 + kk]);  // W_tcn[o][o'][kk][0]
        }
        return;
    }

    // pad 65: adjs[h*65+k] -> bank (h+k)&31 => 2-way (free)
    __shared__ __align__(16) float adjs[64 * 65];
    __shared__ float wl[128];

    const int n = bid >> 7;                       // 128 blocks per n
    const int t = (bid & 127) * 4 + (tid >> 6);   // one t per wave
    const int h = tid & 63;

    {
        f32x4 z4 = {0.f, 0.f, 0.f, 0.f};
        for (int i = tid; i < 1040; i += 256) *(f32x4*)(&adjs[i * 4]) = z4;
    }
    if (tid < 128) wl[tid] = (tid < 64) ? w1g[tid] : w2g[tid - 64];
    __syncthreads();
    {
        int r = edges[n * 512 + tid];        // edges[n][0][e]
        int c = edges[n * 512 + 256 + tid];  // edges[n][1][e]
        atomicAdd(&adjs[r * 65 + c], 1.0f);
    }
    __syncthreads();

    // a1[h], a2[h]: per-lane dot over c (w1/w2 broadcast from LDS)
    const float* Xr = X + ((size_t)(n * 512 + t) * 64 + h) * 64;
    float a1 = b1g[0], a2 = b2g[0];
#pragma unroll 4
    for (int c4 = 0; c4 < 16; c4++) {
        float4 xv = *(const float4*)(Xr + c4 * 4);
        float4 w1v = *(const float4*)(&wl[c4 * 4]);
        float4 w2v = *(const float4*)(&wl[64 + c4 * 4]);
        a1 += xv.x * w1v.x + xv.y * w1v.y + xv.z * w1v.z + xv.w * w1v.w;
        a2 += xv.x * w2v.x + xv.y * w2v.y + xv.z * w2v.z + xv.w * w2v.w;
    }

    // diag[h] = sum_k adj[h,k] e(k,h) / sum_k e(k,h) + 1,
    // e(k,h) = exp(leaky(a1[k] + a2[h])); a1[k] via __shfl (wave64)
    float num = 0.f, den = 0.f;
    const float* arow = &adjs[h * 65];
#pragma unroll
    for (int k = 0; k < 64; k++) {
        float s = __shfl(a1, k) + a2;
        s = fmaxf(s, 0.01f * s);   // leaky_relu(0.01)
        float e = __expf(s);
        den += e;
        num = fmaf(arow[k], e, num);
    }
    diag[((size_t)(n * 64 + h)) * 512 + t] = num / den + 1.0f;
}

// ---------------------------------------------------------------- k_gcn_tcn
// One block per (n, h, quarter-T=128). Wave-local stage+support (no barrier
// between a wave's staging and its own support tiles); single block barrier
// before the K=9 temporal-conv GEMM; epilogue BN2 + f32 residual + ReLU.
__global__ __launch_bounds__(256) void k_gcn_tcn(
    const float* __restrict__ X, const float* __restrict__ diag,
    const u16* __restrict__ wlin_p, const float* __restrict__ blin,
    const float* __restrict__ g1, const float* __restrict__ be1,
    const u16* __restrict__ wtcn_p, const float* __restrict__ btcn,
    const float* __restrict__ g2, const float* __restrict__ be2,
    float* __restrict__ out) {
    __shared__ __align__(16) u16 As[144 * 72];  // row r <-> t = tb-4+r, pad 72

    const int tid = threadIdx.x;
    const int bid = blockIdx.x;
    const int n = bid >> 8, h = (bid >> 2) & 63, tb = (bid & 3) * 128;
    const float* Xbase = X + ((size_t)(n * 512) * 64 + h) * 64;  // + t*4096 + c
    const float* diagb = diag + ((size_t)(n * 64 + h)) * 512;

    const int w = tid >> 6, l = tid & 63;
    const int col = l & 15, q = l >> 4;
    const float rsf = 1.0f / sqrtf(1.0f + 1e-5f);
    const f32x4 zv = {0.f, 0.f, 0.f, 0.f};

    // wave w owns support tiles mt = w, w+4, (w==0: 8): stage own rows,
    // MFMA immediately (same-wave LDS dep => lgkmcnt only, no barrier)
    for (int mt = w; mt < 9; mt += 4) {
#pragma unroll
        for (int i = 0; i < 4; i++) {
            int idx = l + 64 * i;                 // 16 rows * 16 quads
            int r = 16 * mt + (idx >> 4), c4 = idx & 15;
            int tg = tb - 4 + r;
            float4 xv = make_float4(0.f, 0.f, 0.f, 0.f);
            if (tg >= 0 && tg < 512) xv = *(const float4*)(Xbase + (size_t)tg * 4096 + c4 * 4);
            bf16x4 pk;
            pk[0] = (__bf16)xv.x; pk[1] = (__bf16)xv.y;
            pk[2] = (__bf16)xv.z; pk[3] = (__bf16)xv.w;   // v_cvt_pk_bf16_f32
            *(bf16x4*)(&As[r * 72 + c4 * 4]) = pk;
        }
        // per-lane diag prefetch for this tile's output rows (L2)
        float dg[4];
#pragma unroll
        for (int rr = 0; rr < 4; rr++) {
            int tg = tb - 4 + 16 * mt + q * 4 + rr;
            dg[rr] = (tg >= 0 && tg < 512) ? diagb[tg] : 0.f;
        }
        f32x4 acc[4] = {zv, zv, zv, zv};
#pragma unroll
        for (int s = 0; s < 2; s++) {
            bf16x8 a = *(const bf16x8*)(&As[(16 * mt + col) * 72 + s * 32 + q * 8]);
#pragma unroll
            for (int j = 0; j < 4; j++) {
                bf16x8 b = *(const bf16x8*)(&wlin_p[((s * 4 + j) * 64 + l) * 8]);
                acc[j] = __builtin_amdgcn_mfma_f32_16x16x32_bf16(a, b, acc[j], 0, 0, 0);
            }
        }
#pragma unroll
        for (int j = 0; j < 4; j++) {
            int o = 16 * j + col;
            float s1 = g1[o] * rsf;
            float bb = be1[o];
            float bl = blin[o];
#pragma unroll
            for (int rr = 0; rr < 4; rr++) {
                int row = 16 * mt + q * 4 + rr;
                int tg = tb - 4 + row;
                float v = (acc[j][rr] + bl) * dg[rr] * s1 + bb;
                v = v > 0.f ? v : 0.f;
                if (tg < 0 || tg >= 512) v = 0.f;  // conv halo must be zero
                __bf16 bv = (__bf16)v;
                As[row * 72 + o] = __builtin_bit_cast(u16, bv);
            }
        }
    }
    __syncthreads();

    // temporal conv: wave w -> output local rows [32w, 32w+32)
    f32x4 acc2[2][4];
#pragma unroll
    for (int mt = 0; mt < 2; mt++)
#pragma unroll
        for (int j = 0; j < 4; j++) acc2[mt][j] = zv;

    for (int kk = 0; kk < 9; kk++) {
#pragma unroll
        for (int s = 0; s < 2; s++) {
            bf16x8 b[4];
#pragma unroll
            for (int j = 0; j < 4; j++)
                b[j] = *(const bf16x8*)(&wtcn_p[(((kk * 2 + s) * 4 + j) * 64 + l) * 8]);
            bf16x8 a[2];
#pragma unroll
            for (int mt = 0; mt < 2; mt++) {
                int row = 32 * w + 16 * mt + col + kk;  // <= 135
                a[mt] = *(const bf16x8*)(&As[row * 72 + s * 32 + q * 8]);
            }
#pragma unroll
            for (int mt = 0; mt < 2; mt++)
#pragma unroll
                for (int j = 0; j < 4; j++)
                    acc2[mt][j] = __builtin_amdgcn_mfma_f32_16x16x32_bf16(a[mt], b[j], acc2[mt][j], 0, 0, 0);
        }
    }

    // epilogue: BN2(+bias) + residual X (f32, L2-warm) + ReLU
    float s2[4], c2[4];
#pragma unroll
    for (int j = 0; j < 4; j++) {
        int o = 16 * j + col;
        float s = g2[o] * rsf;
        s2[j] = s;
        c2[j] = btcn[o] * s + be2[o];
    }
#pragma unroll
    for (int mt = 0; mt < 2; mt++) {
#pragma unroll
        for (int rr = 0; rr < 4; rr++) {
            int tt = tb + 32 * w + 16 * mt + 4 * q + rr;
#pragma unroll
            for (int j = 0; j < 4; j++) {
                int o = 16 * j + col;
                size_t off = ((size_t)(n * 512 + tt) * 64 + h) * 64 + o;
                float v = acc2[mt][j][rr] * s2[j] + c2[j] + X[off];
                out[off] = v > 0.f ? v : 0.f;
            }
        }
    }
}

// ---------------------------------------------------------------- launch
extern "C" void kernel_launch(void* const* d_in, const int* in_sizes, int n_in,
                              void* d_out, int out_size, void* d_ws, size_t ws_size,
                              hipStream_t stream) {
    const float* X    = (const float*)d_in[0];
    const int*  edges = (const int*)d_in[1];
    const float* w1   = (const float*)d_in[2];
    const float* b1   = (const float*)d_in[3];
    const float* w2   = (const float*)d_in[4];
    const float* b2   = (const float*)d_in[5];
    const float* Wlin = (const float*)d_in[6];
    const float* blin = (const float*)d_in[7];
    const float* g1   = (const float*)d_in[8];
    const float* be1  = (const float*)d_in[9];
    const float* Wtcn = (const float*)d_in[10];
    const float* btcn = (const float*)d_in[11];
    const float* g2   = (const float*)d_in[12];
    const float* be2  = (const float*)d_in[13];
    float* out = (float*)d_out;

    char* ws = (char*)d_ws;
    u16*   wlin_p = (u16*)ws;                          // 8192 B
    u16*   wtcn_p = (u16*)(ws + 8192);                 // 73728 B
    float* diag   = (float*)(ws + 8192 + 73728);       // 2097152 B

    hipLaunchKernelGGL(k_attn, dim3(NB_ATTN + 160), dim3(256), 0, stream,
                       X, edges, w1, b1, w2, b2, Wlin, Wtcn, wlin_p, wtcn_p, diag);
    hipLaunchKernelGGL(k_gcn_tcn, dim3(16 * 64 * 4), dim3(256), 0, stream,
                       X, diag, wlin_p, blin, g1, be1, wtcn_p, btcn, g2, be2, out);
}

// Round 2
// 321.307 us; speedup vs baseline: 1.0436x; 1.0436x over previous
//
#include <hip/hip_runtime.h>
#include <hip/hip_bf16.h>
#include <stdint.h>

// Problem constants: N=16, T=512, H=C=O=64, K=9, E=256
typedef float f32x4 __attribute__((ext_vector_type(4)));
typedef __bf16 bf16x8 __attribute__((ext_vector_type(8)));
typedef __bf16 bf16x4 __attribute__((ext_vector_type(4)));
typedef unsigned short u16;
typedef unsigned int u32;

__device__ __forceinline__ u16 f2bf(float f) {
    u32 u = __float_as_uint(f);
    u32 r = (u + 0x7fffu + ((u >> 16) & 1u)) >> 16;
    return (u16)r;
}

// ---------------------------------------------------------------- k_attn
// Block = (n, group of 4 t). Coalesced X loads + 16-lane butterfly for
// a1/a2; adj built in LDS from edges (transposed: adjT[k][h]) so the
// per-lane softmax read is conflict-free; wave w owns t = tg*4+w.
// Appended blocks (bid >= NB_ATTN) do the weight pack (former k_pack).
#define NB_ATTN 2048

__global__ __launch_bounds__(256) void k_attn(
    const float* __restrict__ X, const int* __restrict__ edges,
    const float* __restrict__ w1g, const float* __restrict__ b1g,
    const float* __restrict__ w2g, const float* __restrict__ b2g,
    const float* __restrict__ Wlin, const float* __restrict__ Wtcn,
    u16* __restrict__ wlin_p, u16* __restrict__ wtcn_p,
    float* __restrict__ diag) {
    const int tid = threadIdx.x;
    const int bid = blockIdx.x;

    if (bid >= NB_ATTN) {
        // ---- weight pack (former k_pack), MFMA B-fragment order ----
        int idx = (bid - NB_ATTN) * 256 + tid;
        if (idx < 4096) {
            int jj = idx & 7, l = (idx >> 3) & 63, j = (idx >> 9) & 3, s = idx >> 11;
            int o = j * 16 + (l & 15);
            int c = s * 32 + (l >> 4) * 8 + jj;
            wlin_p[idx] = f2bf(Wlin[o * 64 + c]);
        }
        int i2 = idx - 4096;
        if (i2 >= 0 && i2 < 36864) {
            int jj = i2 & 7, l = (i2 >> 3) & 63, j = (i2 >> 9) & 3, s = (i2 >> 11) & 1, kk = i2 >> 12;
            int o = j * 16 + (l & 15);
            int op = s * 32 + (l >> 4) * 8 + jj;
            wtcn_p[i2] = f2bf(Wtcn[(o * 64 + op) * 9 + kk]);  // W_tcn[o][o'][kk][0]
        }
        return;
    }

    // adjT[k*65 + h] = adj[h][k]; bank (k+h)&31 -> 2-way across 64 lanes (free)
    __shared__ __align__(16) float adjT[64 * 65];
    __shared__ __align__(16) float A1s[4][64], A2s[4][64];

    const int n = bid >> 7;        // 128 blocks per n
    const int tg = bid & 127;
    const int w = tid >> 6, l = tid & 63;
    const int t = tg * 4 + w;      // one t per wave
    const int c4 = l & 15, q = l >> 4;

    {
        f32x4 z4 = {0.f, 0.f, 0.f, 0.f};
        for (int i = tid; i < 1040; i += 256) *(f32x4*)(&adjT[i * 4]) = z4;
    }
    __syncthreads();
    {
        int r = edges[n * 512 + tid];        // edges[n][0][e]
        int c = edges[n * 512 + 256 + tid];  // edges[n][1][e]
        atomicAdd(&adjT[c * 65 + r], 1.0f);  // transposed store
    }

    // ---- a1/a2: coalesced loads, butterfly reduce over the 16-lane c4 group
    // iter i covers h = i*4 + q; lane keeps the i matching its c4 slot.
    const float* Xt = X + (size_t)(n * 512 + t) * 4096;
    const float4 w1v = *(const float4*)(w1g + c4 * 4);
    const float4 w2v = *(const float4*)(w2g + c4 * 4);
    float a1h = 0.f, a2h = 0.f;
#pragma unroll 8
    for (int i = 0; i < 16; i++) {
        float4 xv = *(const float4*)(Xt + (i * 64 + l) * 4);  // 1KB/instr contiguous
        float p1 = xv.x * w1v.x + xv.y * w1v.y + xv.z * w1v.z + xv.w * w1v.w;
        float p2 = xv.x * w2v.x + xv.y * w2v.y + xv.z * w2v.z + xv.w * w2v.w;
        p1 += __shfl_xor(p1, 1); p1 += __shfl_xor(p1, 2);
        p1 += __shfl_xor(p1, 4); p1 += __shfl_xor(p1, 8);
        p2 += __shfl_xor(p2, 1); p2 += __shfl_xor(p2, 2);
        p2 += __shfl_xor(p2, 4); p2 += __shfl_xor(p2, 8);
        if (c4 == i) { a1h = p1; a2h = p2; }
    }
    {
        int hh = c4 * 4 + q;  // the h this lane ended up holding
        A1s[w][hh] = a1h + b1g[0];
        A2s[w][hh] = a2h + b2g[0];
    }
    __syncthreads();  // covers adj atomics + A1s/A2s

    // ---- softmax over k: lane l <-> h=l; A1s[w][k] is an LDS broadcast
    {
        float a2 = A2s[w][l];
        float num = 0.f, den = 0.f;
#pragma unroll 16
        for (int k = 0; k < 64; k++) {
            float s = A1s[w][k] + a2;
            s = fmaxf(s, 0.01f * s);  // leaky_relu(0.01)
            float e = __expf(s);
            den += e;
            num = fmaf(adjT[k * 65 + l], e, num);
        }
        diag[((size_t)(n * 64 + l)) * 512 + t] = num / den + 1.0f;
    }
}

// ---------------------------------------------------------------- k_gcn_tcn
// One block per (n, h, quarter-T=128). Cooperative coalesced staging (9
// independent float4 loads/thread -> high MLP), one barrier, support GEMM
// in place, barrier, K=9 temporal conv GEMM, epilogue BN2 + residual + ReLU.
__global__ __launch_bounds__(256) void k_gcn_tcn(
    const float* __restrict__ X, const float* __restrict__ diag,
    const u16* __restrict__ wlin_p, const float* __restrict__ blin,
    const float* __restrict__ g1, const float* __restrict__ be1,
    const u16* __restrict__ wtcn_p, const float* __restrict__ btcn,
    const float* __restrict__ g2, const float* __restrict__ be2,
    float* __restrict__ out) {
    __shared__ __align__(16) u16 As[144 * 72];  // row r <-> t = tb-4+r, pad 72
    __shared__ float DGs[144];

    const int tid = threadIdx.x;
    const int bid = blockIdx.x;
    const int n = bid >> 8, h = (bid >> 2) & 63, tb = (bid & 3) * 128;
    const float* Xbase = X + ((size_t)(n * 512) * 64 + h) * 64;  // + t*4096 + c

    // stage X (f32 -> bf16 via v_cvt_pk), zero halo outside [0,512)
#pragma unroll
    for (int i = 0; i < 9; i++) {
        int idx = tid + 256 * i;  // 144 rows * 16 quads = 2304
        int r = idx >> 4, c4 = idx & 15;
        int tg = tb - 4 + r;
        float4 xv = make_float4(0.f, 0.f, 0.f, 0.f);
        if (tg >= 0 && tg < 512) xv = *(const float4*)(Xbase + (size_t)tg * 4096 + c4 * 4);
        bf16x4 pk;
        pk[0] = (__bf16)xv.x; pk[1] = (__bf16)xv.y;
        pk[2] = (__bf16)xv.z; pk[3] = (__bf16)xv.w;
        *(bf16x4*)(&As[r * 72 + c4 * 4]) = pk;
    }
    if (tid < 144) {
        int tg = tb - 4 + tid;
        DGs[tid] = (tg >= 0 && tg < 512) ? diag[((size_t)(n * 64 + h)) * 512 + tg] : 0.f;
    }
    __syncthreads();

    const int w = tid >> 6, l = tid & 63;
    const int col = l & 15, q = l >> 4;
    const float rsf = 1.0f / sqrtf(1.0f + 1e-5f);
    const f32x4 zv = {0.f, 0.f, 0.f, 0.f};

    // support GEMM, z written in place over X rows (wave-private m-tiles)
    for (int mt = w; mt < 9; mt += 4) {
        f32x4 acc[4] = {zv, zv, zv, zv};
#pragma unroll
        for (int s = 0; s < 2; s++) {
            bf16x8 a = *(const bf16x8*)(&As[(16 * mt + col) * 72 + s * 32 + q * 8]);
#pragma unroll
            for (int j = 0; j < 4; j++) {
                bf16x8 b = *(const bf16x8*)(&wlin_p[((s * 4 + j) * 64 + l) * 8]);
                acc[j] = __builtin_amdgcn_mfma_f32_16x16x32_bf16(a, b, acc[j], 0, 0, 0);
            }
        }
#pragma unroll
        for (int j = 0; j < 4; j++) {
            int o = 16 * j + col;
            float s1 = g1[o] * rsf;
            float bb = be1[o];
            float bl = blin[o];
#pragma unroll
            for (int rr = 0; rr < 4; rr++) {
                int row = 16 * mt + q * 4 + rr;
                int tg = tb - 4 + row;
                float v = (acc[j][rr] + bl) * DGs[row] * s1 + bb;
                v = v > 0.f ? v : 0.f;
                if (tg < 0 || tg >= 512) v = 0.f;  // conv halo must be zero
                __bf16 bv = (__bf16)v;
                As[row * 72 + o] = __builtin_bit_cast(u16, bv);
            }
        }
    }
    __syncthreads();

    // temporal conv: wave w -> output local rows [32w, 32w+32)
    f32x4 acc2[2][4];
#pragma unroll
    for (int mt = 0; mt < 2; mt++)
#pragma unroll
        for (int j = 0; j < 4; j++) acc2[mt][j] = zv;

    for (int kk = 0; kk < 9; kk++) {
#pragma unroll
        for (int s = 0; s < 2; s++) {
            bf16x8 b[4];
#pragma unroll
            for (int j = 0; j < 4; j++)
                b[j] = *(const bf16x8*)(&wtcn_p[(((kk * 2 + s) * 4 + j) * 64 + l) * 8]);
            bf16x8 a[2];
#pragma unroll
            for (int mt = 0; mt < 2; mt++) {
                int row = 32 * w + 16 * mt + col + kk;  // <= 135
                a[mt] = *(const bf16x8*)(&As[row * 72 + s * 32 + q * 8]);
            }
#pragma unroll
            for (int mt = 0; mt < 2; mt++)
#pragma unroll
                for (int j = 0; j < 4; j++)
                    acc2[mt][j] = __builtin_amdgcn_mfma_f32_16x16x32_bf16(a[mt], b[j], acc2[mt][j], 0, 0, 0);
        }
    }

    // epilogue: BN2(+bias) + residual X (f32, L2-warm) + ReLU
    float s2[4], c2[4];
#pragma unroll
    for (int j = 0; j < 4; j++) {
        int o = 16 * j + col;
        float s = g2[o] * rsf;
        s2[j] = s;
        c2[j] = btcn[o] * s + be2[o];
    }
#pragma unroll
    for (int mt = 0; mt < 2; mt++) {
#pragma unroll
        for (int rr = 0; rr < 4; rr++) {
            int tt = tb + 32 * w + 16 * mt + 4 * q + rr;
#pragma unroll
            for (int j = 0; j < 4; j++) {
                int o = 16 * j + col;
                size_t off = ((size_t)(n * 512 + tt) * 64 + h) * 64 + o;
                float v = acc2[mt][j][rr] * s2[j] + c2[j] + X[off];
                out[off] = v > 0.f ? v : 0.f;
            }
        }
    }
}

// ---------------------------------------------------------------- launch
extern "C" void kernel_launch(void* const* d_in, const int* in_sizes, int n_in,
                              void* d_out, int out_size, void* d_ws, size_t ws_size,
                              hipStream_t stream) {
    const float* X    = (const float*)d_in[0];
    const int*  edges = (const int*)d_in[1];
    const float* w1   = (const float*)d_in[2];
    const float* b1   = (const float*)d_in[3];
    const float* w2   = (const float*)d_in[4];
    const float* b2   = (const float*)d_in[5];
    const float* Wlin = (const float*)d_in[6];
    const float* blin = (const float*)d_in[7];
    const float* g1   = (const float*)d_in[8];
    const float* be1  = (const float*)d_in[9];
    const float* Wtcn = (const float*)d_in[10];
    const float* btcn = (const float*)d_in[11];
    const float* g2   = (const float*)d_in[12];
    const float* be2  = (const float*)d_in[13];
    float* out = (float*)d_out;

    char* ws = (char*)d_ws;
    u16*   wlin_p = (u16*)ws;                          // 8192 B
    u16*   wtcn_p = (u16*)(ws + 8192);                 // 73728 B
    float* diag   = (float*)(ws + 8192 + 73728);       // 2097152 B

    hipLaunchKernelGGL(k_attn, dim3(NB_ATTN + 160), dim3(256), 0, stream,
                       X, edges, w1, b1, w2, b2, Wlin, Wtcn, wlin_p, wtcn_p, diag);
    hipLaunchKernelGGL(k_gcn_tcn, dim3(16 * 64 * 4), dim3(256), 0, stream,
                       X, diag, wlin_p, blin, g1, be1, wtcn_p, btcn, g2, be2, out);
}

// Round 3
// 319.774 us; speedup vs baseline: 1.0486x; 1.0048x over previous
//
#include <hip/hip_runtime.h>
#include <hip/hip_bf16.h>
#include <stdint.h>

// Problem constants: N=16, T=512, H=C=O=64, K=9, E=256
typedef float f32x4 __attribute__((ext_vector_type(4)));
typedef __bf16 bf16x8 __attribute__((ext_vector_type(8)));
typedef __bf16 bf16x4 __attribute__((ext_vector_type(4)));
typedef unsigned short u16;
typedef unsigned int u32;

__device__ __forceinline__ u16 f2bf(float f) {
    u32 u = __float_as_uint(f);
    u32 r = (u + 0x7fffu + ((u >> 16) & 1u)) >> 16;
    return (u16)r;
}

// DPP row_ror:N within 16-lane rows — VALU-pipe lane rotate (no LDS traffic)
template <int CTRL>
__device__ __forceinline__ float rrot(float x) {
    int r = __builtin_amdgcn_update_dpp(0, __builtin_bit_cast(int, x), CTRL, 0xF, 0xF, false);
    return __builtin_bit_cast(float, r);
}
// sum over the 16-lane row via rotations (all 16 lanes end with the total)
__device__ __forceinline__ float rowsum16(float p) {
    p += rrot<0x128>(p);  // ror 8
    p += rrot<0x124>(p);  // ror 4
    p += rrot<0x122>(p);  // ror 2
    p += rrot<0x121>(p);  // ror 1
    return p;
}

// ---------------------------------------------------------------- k_attn
// Block = (n, 4 t's). Coalesced X loads; 16-lane DPP row reduction for
// a1/a2 (VALU pipe, replaces ds_bpermute butterfly); adj built in LDS from
// edges (transposed adjT[k][h]); wave w owns t = tg*4+w.
// Appended blocks: weight pack (pre-scaled by BN gammas) + aux constants.
#define NB_ATTN 2048

__global__ __launch_bounds__(256) void k_attn(
    const float* __restrict__ X, const int* __restrict__ edges,
    const float* __restrict__ w1g, const float* __restrict__ b1g,
    const float* __restrict__ w2g, const float* __restrict__ b2g,
    const float* __restrict__ Wlin, const float* __restrict__ Wtcn,
    const float* __restrict__ blin, const float* __restrict__ g1,
    const float* __restrict__ be1, const float* __restrict__ btcn,
    const float* __restrict__ g2, const float* __restrict__ be2,
    u16* __restrict__ wlin_p, u16* __restrict__ wtcn_p,
    float* __restrict__ aux, float* __restrict__ diag) {
    const int tid = threadIdx.x;
    const int bid = blockIdx.x;
    const float rsf = 1.0f / sqrtf(1.0f + 1e-5f);

    if (bid >= NB_ATTN) {
        // ---- weight pack, MFMA B-fragment order, BN scale folded in ----
        int idx = (bid - NB_ATTN) * 256 + tid;
        if (idx < 4096) {
            int jj = idx & 7, l = (idx >> 3) & 63, j = (idx >> 9) & 3, s = idx >> 11;
            int o = j * 16 + (l & 15);
            int c = s * 32 + (l >> 4) * 8 + jj;
            wlin_p[idx] = f2bf(Wlin[o * 64 + c] * (g1[o] * rsf));
        }
        int i2 = idx - 4096;
        if (i2 >= 0 && i2 < 36864) {
            int jj = i2 & 7, l = (i2 >> 3) & 63, j = (i2 >> 9) & 3, s = (i2 >> 11) & 1, kk = i2 >> 12;
            int o = j * 16 + (l & 15);
            int op = s * 32 + (l >> 4) * 8 + jj;
            wtcn_p[i2] = f2bf(Wtcn[(o * 64 + op) * 9 + kk] * (g2[o] * rsf));
        }
        if (idx >= 40960 && tid < 64) {
            // aux: [0,64) blin*s1; [64,128) be1; [128,192) btcn*s2+be2
            aux[tid] = blin[tid] * g1[tid] * rsf;
            aux[64 + tid] = be1[tid];
            aux[128 + tid] = btcn[tid] * g2[tid] * rsf + be2[tid];
        }
        return;
    }

    // adjT[k*65 + h] = adj[h][k]; bank (k+h)&31 -> 2-way across 64 lanes (free)
    __shared__ __align__(16) float adjT[64 * 65];
    __shared__ __align__(16) float A1s[4][64], A2s[4][64];

    const int n = bid >> 7;        // 128 blocks per n
    const int tg = bid & 127;
    const int w = tid >> 6, l = tid & 63;
    const int t = tg * 4 + w;      // one t per wave
    const int c4 = l & 15, q = l >> 4;

    {
        f32x4 z4 = {0.f, 0.f, 0.f, 0.f};
        for (int i = tid; i < 1040; i += 256) *(f32x4*)(&adjT[i * 4]) = z4;
    }
    __syncthreads();
    {
        int r = edges[n * 512 + tid];        // edges[n][0][e]
        int c = edges[n * 512 + 256 + tid];  // edges[n][1][e]
        atomicAdd(&adjT[c * 65 + r], 1.0f);  // transposed store
    }

    // ---- a1/a2: coalesced loads + DPP row reduction (VALU pipe only)
    const float* Xt = X + (size_t)(n * 512 + t) * 4096;
    const float4 w1v = *(const float4*)(w1g + c4 * 4);
    const float4 w2v = *(const float4*)(w2g + c4 * 4);
    float a1h = 0.f, a2h = 0.f;
#pragma unroll 8
    for (int i = 0; i < 16; i++) {
        float4 xv = *(const float4*)(Xt + (i * 64 + l) * 4);  // 1KB/instr contiguous
        float p1 = xv.x * w1v.x + xv.y * w1v.y + xv.z * w1v.z + xv.w * w1v.w;
        float p2 = xv.x * w2v.x + xv.y * w2v.y + xv.z * w2v.z + xv.w * w2v.w;
        p1 = rowsum16(p1);
        p2 = rowsum16(p2);
        if (c4 == i) { a1h = p1; a2h = p2; }
    }
    {
        int hh = c4 * 4 + q;  // the h this lane holds
        A1s[w][hh] = a1h + b1g[0];
        A2s[w][hh] = a2h + b2g[0];
    }
    __syncthreads();  // covers adj atomics + A1s/A2s

    // ---- softmax over k: lane l <-> h=l; A1s read as broadcast float4
    {
        float a2 = A2s[w][l];
        float num = 0.f, den = 0.f;
#pragma unroll
        for (int k4 = 0; k4 < 16; k4++) {
            float4 a1v = *(const float4*)(&A1s[w][k4 * 4]);
#pragma unroll
            for (int j = 0; j < 4; j++) {
                int k = k4 * 4 + j;
                float s = ((const float*)&a1v)[j] + a2;
                s = fmaxf(s, 0.01f * s);  // leaky_relu(0.01)
                float e = __expf(s);
                den += e;
                num = fmaf(adjT[k * 65 + l], e, num);
            }
        }
        diag[((size_t)(n * 64 + l)) * 512 + t] = num / den + 1.0f;
    }
}

// ---------------------------------------------------------------- k_gcn_tcn
// One block per (n, h, quarter-T=128). Cooperative staging, support GEMM
// in place (weights pre-scaled by BN1), barrier, K=9 conv GEMM (pre-scaled
// by BN2), epilogue add-const + batched residual + ReLU.
__global__ __launch_bounds__(256) void k_gcn_tcn(
    const float* __restrict__ X, const float* __restrict__ diag,
    const u16* __restrict__ wlin_p, const u16* __restrict__ wtcn_p,
    const float* __restrict__ aux, float* __restrict__ out) {
    __shared__ __align__(16) u16 As[144 * 72];  // row r <-> t = tb-4+r, pad 72
    __shared__ float DGs[144];

    const int tid = threadIdx.x;
    const int bid = blockIdx.x;
    const int n = bid >> 8, h = (bid >> 2) & 63, tb = (bid & 3) * 128;
    const float* Xbase = X + ((size_t)(n * 512) * 64 + h) * 64;  // + t*4096 + c

    // stage X (f32 -> bf16 via v_cvt_pk), zero halo outside [0,512)
#pragma unroll
    for (int i = 0; i < 9; i++) {
        int idx = tid + 256 * i;  // 144 rows * 16 quads = 2304
        int r = idx >> 4, c4 = idx & 15;
        int tg = tb - 4 + r;
        float4 xv = make_float4(0.f, 0.f, 0.f, 0.f);
        if (tg >= 0 && tg < 512) xv = *(const float4*)(Xbase + (size_t)tg * 4096 + c4 * 4);
        bf16x4 pk;
        pk[0] = (__bf16)xv.x; pk[1] = (__bf16)xv.y;
        pk[2] = (__bf16)xv.z; pk[3] = (__bf16)xv.w;
        *(bf16x4*)(&As[r * 72 + c4 * 4]) = pk;
    }
    if (tid < 144) {
        int tg = tb - 4 + tid;
        DGs[tid] = (tg >= 0 && tg < 512) ? diag[((size_t)(n * 64 + h)) * 512 + tg] : 0.f;
    }

    const int w = tid >> 6, l = tid & 63;
    const int col = l & 15, q = l >> 4;
    const f32x4 zv = {0.f, 0.f, 0.f, 0.f};

    // per-lane epilogue constants (L2-resident aux; latency hides under stage)
    float blp[4], bb1[4], cc2[4];
#pragma unroll
    for (int j = 0; j < 4; j++) {
        int o = 16 * j + col;
        blp[j] = aux[o];
        bb1[j] = aux[64 + o];
        cc2[j] = aux[128 + o];
    }
    __syncthreads();

    // support GEMM, z written in place over X rows (wave-private m-tiles)
    for (int mt = w; mt < 9; mt += 4) {
        f32x4 acc[4] = {zv, zv, zv, zv};
#pragma unroll
        for (int s = 0; s < 2; s++) {
            bf16x8 a = *(const bf16x8*)(&As[(16 * mt + col) * 72 + s * 32 + q * 8]);
#pragma unroll
            for (int j = 0; j < 4; j++) {
                bf16x8 b = *(const bf16x8*)(&wlin_p[((s * 4 + j) * 64 + l) * 8]);
                acc[j] = __builtin_amdgcn_mfma_f32_16x16x32_bf16(a, b, acc[j], 0, 0, 0);
            }
        }
#pragma unroll
        for (int j = 0; j < 4; j++) {
#pragma unroll
            for (int rr = 0; rr < 4; rr++) {
                int row = 16 * mt + q * 4 + rr;
                int tg = tb - 4 + row;
                float v = fmaf(acc[j][rr] + blp[j], DGs[row], bb1[j]);
                v = v > 0.f ? v : 0.f;
                if (tg < 0 || tg >= 512) v = 0.f;  // conv halo must be zero
                __bf16 bv = (__bf16)v;
                As[row * 72 + 16 * j + col] = __builtin_bit_cast(u16, bv);
            }
        }
    }
    __syncthreads();

    // temporal conv: wave w -> output local rows [32w, 32w+32)
    f32x4 acc2[2][4];
#pragma unroll
    for (int mt = 0; mt < 2; mt++)
#pragma unroll
        for (int j = 0; j < 4; j++) acc2[mt][j] = zv;

    for (int kk = 0; kk < 9; kk++) {
#pragma unroll
        for (int s = 0; s < 2; s++) {
            bf16x8 b[4];
#pragma unroll
            for (int j = 0; j < 4; j++)
                b[j] = *(const bf16x8*)(&wtcn_p[(((kk * 2 + s) * 4 + j) * 64 + l) * 8]);
            bf16x8 a[2];
#pragma unroll
            for (int mt = 0; mt < 2; mt++) {
                int row = 32 * w + 16 * mt + col + kk;  // <= 135
                a[mt] = *(const bf16x8*)(&As[row * 72 + s * 32 + q * 8]);
            }
#pragma unroll
            for (int mt = 0; mt < 2; mt++)
#pragma unroll
                for (int j = 0; j < 4; j++)
                    acc2[mt][j] = __builtin_amdgcn_mfma_f32_16x16x32_bf16(a[mt], b[j], acc2[mt][j], 0, 0, 0);
        }
    }

    // epilogue: +const (BN2 pre-folded) + batched f32 residual + ReLU
#pragma unroll
    for (int mt = 0; mt < 2; mt++) {
        float res[4][4];
#pragma unroll
        for (int rr = 0; rr < 4; rr++) {
            int tt = tb + 32 * w + 16 * mt + 4 * q + rr;
#pragma unroll
            for (int j = 0; j < 4; j++)
                res[j][rr] = X[((size_t)(n * 512 + tt) * 64 + h) * 64 + 16 * j + col];
        }
#pragma unroll
        for (int rr = 0; rr < 4; rr++) {
            int tt = tb + 32 * w + 16 * mt + 4 * q + rr;
#pragma unroll
            for (int j = 0; j < 4; j++) {
                size_t off = ((size_t)(n * 512 + tt) * 64 + h) * 64 + 16 * j + col;
                float v = acc2[mt][j][rr] + cc2[j] + res[j][rr];
                out[off] = v > 0.f ? v : 0.f;
            }
        }
    }
}

// ---------------------------------------------------------------- launch
extern "C" void kernel_launch(void* const* d_in, const int* in_sizes, int n_in,
                              void* d_out, int out_size, void* d_ws, size_t ws_size,
                              hipStream_t stream) {
    const float* X    = (const float*)d_in[0];
    const int*  edges = (const int*)d_in[1];
    const float* w1   = (const float*)d_in[2];
    const float* b1   = (const float*)d_in[3];
    const float* w2   = (const float*)d_in[4];
    const float* b2   = (const float*)d_in[5];
    const float* Wlin = (const float*)d_in[6];
    const float* blin = (const float*)d_in[7];
    const float* g1   = (const float*)d_in[8];
    const float* be1  = (const float*)d_in[9];
    const float* Wtcn = (const float*)d_in[10];
    const float* btcn = (const float*)d_in[11];
    const float* g2   = (const float*)d_in[12];
    const float* be2  = (const float*)d_in[13];
    float* out = (float*)d_out;

    char* ws = (char*)d_ws;
    u16*   wlin_p = (u16*)ws;                          // 8192 B
    u16*   wtcn_p = (u16*)(ws + 8192);                 // 73728 B
    float* aux    = (float*)(ws + 8192 + 73728);       // 1024 B
    float* diag   = (float*)(ws + 8192 + 73728 + 1024);// 2097152 B

    hipLaunchKernelGGL(k_attn, dim3(NB_ATTN + 161), dim3(256), 0, stream,
                       X, edges, w1, b1, w2, b2, Wlin, Wtcn,
                       blin, g1, be1, btcn, g2, be2,
                       wlin_p, wtcn_p, aux, diag);
    hipLaunchKernelGGL(k_gcn_tcn, dim3(16 * 64 * 4), dim3(256), 0, stream,
                       X, diag, wlin_p, wtcn_p, aux, out);
}